// Round 4
// baseline (478.104 us; speedup 1.0000x reference)
//
#include <hip/hip_runtime.h>
#include <stdint.h>
#include <stddef.h>

#define NN 64
#define BB 128
#define LL 4096
#define EE 16

typedef __attribute__((ext_vector_type(4))) float f32x4;
typedef __attribute__((ext_vector_type(2))) float f32x2;
typedef __attribute__((ext_vector_type(8))) short short8;
typedef __attribute__((ext_vector_type(4))) unsigned short u16x4;

__device__ __forceinline__ unsigned short f2bf(float f) {
  union { float f; unsigned u; } v; v.f = f;
  unsigned r = v.u + 0x7FFFu + ((v.u >> 16) & 1u);   // RNE
  return (unsigned short)(r >> 16);
}
__device__ __forceinline__ float bf2f(unsigned short h) {
  union { unsigned u; float f; } v; v.u = ((unsigned)h) << 16;
  return v.f;
}
__device__ __forceinline__ void gload16(const void* g, void* l) {
  __builtin_amdgcn_global_load_lds((const __attribute__((address_space(1))) void*)g,
                                   (__attribute__((address_space(3))) void*)l,
                                   16, 0, 0);
}

// ---------------- K1: weight converts: Wm -> bf16, Wl/Wr -> transposed bf16 ----------------
__global__ __launch_bounds__(256) void k_cvtw(const float* __restrict__ Wm,
    const float* __restrict__ Wl, const float* __restrict__ Wr,
    unsigned short* __restrict__ wm_bf, unsigned short* __restrict__ wt_bf) {
  int bid = blockIdx.x;
  if (bid < 2048) {
    int i = bid * 256 + threadIdx.x;
    for (; i < (LL * LL / 4); i += 2048 * 256) {
      f32x4 v = ((const f32x4*)Wm)[i];
      u16x4 o;
      o[0] = f2bf(v[0]); o[1] = f2bf(v[1]); o[2] = f2bf(v[2]); o[3] = f2bf(v[3]);
      ((u16x4*)wm_bf)[i] = o;
    }
  } else {
    // wt_bf[e][k]: e<16 -> Wl[k][e], e>=16 -> Wr[k][e-16]. 32x4096 bf16.
    int u = (bid - 2048) * 256 + threadIdx.x;   // 0..2047
    int e = u >> 6;
    int kb = (u & 63) * 64;
    const float* src = (e < 16) ? (Wl + e) : (Wr + (e - 16));
    for (int k = kb; k < kb + 64; ++k)
      wt_bf[(size_t)e * LL + k] = f2bf(src[(size_t)k * 16]);
  }
}

// ---------------- K2: feat fp32 -> bf16 streaming convert ----------------
__global__ __launch_bounds__(256) void k_cvtf(const float* __restrict__ feat,
                                              unsigned short* __restrict__ feat_bf) {
  int i = blockIdx.x * 256 + threadIdx.x;
  const int n4 = NN * BB * LL / 4;
  for (; i < n4; i += 2048 * 256) {
    f32x4 v = ((const f32x4*)feat)[i];
    u16x4 o;
    o[0] = f2bf(v[0]); o[1] = f2bf(v[1]); o[2] = f2bf(v[2]); o[3] = f2bf(v[3]);
    ((u16x4*)feat_bf)[i] = o;
  }
}

#define MFMA(a, b, c) __builtin_amdgcn_mfma_f32_16x16x32_bf16((a), (b), (c), 0, 0, 0)

// ---------------- K3: att projections via MFMA, K-split x4 ----------------
// attP[kc][row][0..15] = partial feat@Wl ; [16..31] = partial feat@Wr (no bias).
// Direct-global fragments: A from feat_bf, B from wt_bf (L2-hot). No LDS.
__global__ __launch_bounds__(256) void k_attm(const unsigned short* __restrict__ feat_bf,
    const unsigned short* __restrict__ wt_bf, float* __restrict__ attP) {
  const int t = threadIdx.x, lane = t & 63, w = t >> 6;
  const int rowTile = blockIdx.x;   // 0..127 (64 rows each)
  const int kc = blockIdx.y;        // 0..3   (1024 k each)
  const int grow = rowTile * 64 + w * 16 + (lane & 15);
  const int kbase = kc * 1024 + (lane >> 4) * 8;
  const unsigned short* aP  = feat_bf + (size_t)grow * LL + kbase;
  const unsigned short* b0P = wt_bf + (size_t)(lane & 15) * LL + kbase;
  const unsigned short* b1P = wt_bf + (size_t)(16 + (lane & 15)) * LL + kbase;
  f32x4 acc0 = {}, acc1 = {};
  #pragma unroll 4
  for (int ks = 0; ks < 32; ++ks) {
    short8 av = *(const short8*)(aP + ks * 32);
    short8 b0 = *(const short8*)(b0P + ks * 32);
    short8 b1 = *(const short8*)(b1P + ks * 32);
    acc0 = MFMA(av, b0, acc0);
    acc1 = MFMA(av, b1, acc1);
  }
  const int orow = rowTile * 64 + w * 16 + (lane >> 4) * 4;
  const int col = lane & 15;
  float* P = attP + (size_t)kc * (8192 * 32);
  #pragma unroll
  for (int j = 0; j < 4; ++j) {
    P[(size_t)(orow + j) * 32 + col]      = acc0[j];
    P[(size_t)(orow + j) * 32 + 16 + col] = acc1[j];
  }
}

// ---------------- K4: edge scores + BN + softmax ----------------
// Sums the 4 attP partials + bias on the fly.
__global__ __launch_bounds__(256) void k_edge(const float* __restrict__ attP,
    const float* __restrict__ bl, const float* __restrict__ br,
    const float* __restrict__ gamma, const float* __restrict__ beta,
    float* __restrict__ w_t) {
  __shared__ __align__(16) float attr[BB][20];
  __shared__ float el[NN][BB + 1];
  __shared__ float part[NN][4][2];
  __shared__ float sc[NN], sh[NN];
  int d = blockIdx.x, t = threadIdx.x;
  // attr[b][e] = sum_c attP[c][d*128+b][16+e] + br[e]
  for (int i = t; i < 2048; i += 256) {
    int b = i >> 4, e = i & 15;
    float v2 = br[e];
    #pragma unroll
    for (int c = 0; c < 4; ++c)
      v2 += attP[(size_t)c * (8192 * 32) + ((size_t)d * 128 + b) * 32 + 16 + e];
    attr[b][e] = v2;
  }
  float blv[16];
  #pragma unroll
  for (int e = 0; e < 16; ++e) blv[e] = bl[e];
  __syncthreads();
  for (int v = t; v < NN * BB; v += 256) {
    int s = v >> 7, b = v & 127;
    float al[16];
    #pragma unroll
    for (int e = 0; e < 16; ++e) al[e] = blv[e];
    #pragma unroll
    for (int c = 0; c < 4; ++c) {
      const f32x4* p = (const f32x4*)&attP[(size_t)c * (8192 * 32) + ((size_t)s * 128 + b) * 32];
      #pragma unroll
      for (int q = 0; q < 4; ++q) {
        f32x4 x = p[q];
        al[q * 4 + 0] += x[0]; al[q * 4 + 1] += x[1];
        al[q * 4 + 2] += x[2]; al[q * 4 + 3] += x[3];
      }
    }
    float acc = 0.f;
    #pragma unroll
    for (int e = 0; e < 16; ++e) acc += al[e] * attr[b][e];
    el[s][b] = acc;
  }
  __syncthreads();
  {
    int s = t >> 2, q = t & 3;
    float sum = 0.f, ss = 0.f;
    for (int b = q * 32; b < q * 32 + 32; ++b) { float x = el[s][b]; sum += x; ss += x * x; }
    part[s][q][0] = sum; part[s][q][1] = ss;
  }
  __syncthreads();
  if (t < 64) {
    float sum = 0.f, ss = 0.f;
    #pragma unroll
    for (int q = 0; q < 4; ++q) { sum += part[t][q][0]; ss += part[t][q][1]; }
    float mu = sum * (1.f / 128.f);
    float var = ss * (1.f / 128.f) - mu * mu;
    int c = d * 64 + t;
    float a = gamma[c] * rsqrtf(fmaxf(var, 0.f) + 1e-5f);
    sc[t] = a; sh[t] = beta[c] - mu * a;
  }
  __syncthreads();
  if (t < 128) {
    int b = t;
    float y[64];
    float m = -1e30f;
    #pragma unroll
    for (int s = 0; s < 64; ++s) { y[s] = sc[s] * el[s][b] + sh[s]; m = fmaxf(m, y[s]); }
    float sum = 0.f;
    #pragma unroll
    for (int s = 0; s < 64; ++s) { y[s] = __expf(y[s] - m); sum += y[s]; }
    float inv = 1.f / sum;
    float* wp = &w_t[((size_t)b * 64 + d) * 64];
    #pragma unroll
    for (int s4 = 0; s4 < 16; ++s4) {
      f32x4 o;
      o[0] = y[s4 * 4 + 0] * inv; o[1] = y[s4 * 4 + 1] * inv;
      o[2] = y[s4 * 4 + 2] * inv; o[3] = y[s4 * 4 + 3] * inv;
      *(f32x4*)&wp[s4 * 4] = o;
    }
  }
}

// ---------------- K5: 256x256 8-phase bf16 MFMA GEMM ----------------
// R3 change: NO lgkmcnt(0) drain before MFMA. ds_reads are C++ loads, so the
// compiler emits fine-grained lgkmcnt(N) per dependent MFMA — early fragments
// compute while late fragments are still returning (read/MFMA overlap).
// Barriers keep phase lockstep for stage-vs-read discipline; VM6 ("memory")
// fences tile boundaries for the compiler-invisible global_load_lds writes.
#define LDS_A 0
#define LDS_B 65536
#define BAR   __builtin_amdgcn_s_barrier()
#define VM6   asm volatile("s_waitcnt vmcnt(6)" ::: "memory")
#define VM4   asm volatile("s_waitcnt vmcnt(4)" ::: "memory")
#define VM0   asm volatile("s_waitcnt vmcnt(0)" ::: "memory")
#define PRIO1 __builtin_amdgcn_s_setprio(1)
#define PRIO0 __builtin_amdgcn_s_setprio(0)
#define STAGE2(g0, g1, ldsoff) do { \
    gload16((g0), lds_raw + (ldsoff) + tid16); \
    gload16((g1), lds_raw + (ldsoff) + 8192 + tid16); } while (0)

__global__ __launch_bounds__(512, 2) void k_gemm8(const unsigned short* __restrict__ A,
    const unsigned short* __restrict__ Bm, const float* __restrict__ bm,
    unsigned short* __restrict__ C) {
  __shared__ __align__(16) char lds_raw[131072];
  const int tid = threadIdx.x;
  const int lane = tid & 63, wave = tid >> 6;
  const int wm = wave >> 2, wn = wave & 3;
  int bid = blockIdx.x;
  int swz = (bid & 7) * 64 + (bid >> 3);
  int tM = swz >> 4, tN = swz & 15;
  const size_t rowBase = (size_t)tM * 256, colBase = (size_t)tN * 256;
  const int tid16 = tid * 16;
  const int o0 = tid16, o1 = tid16 + 8192;
  const int r0s = (o0 & 1023) >> 6, r1s = (o1 & 1023) >> 6;
  const int row0 = (o0 >> 10) * 16 + r0s, row1 = (o1 >> 10) * 16 + r1s;
  const int col0 = (((o0 >> 4) & 3) ^ ((r0s >> 3) << 1)) * 8;
  const int col1 = (((o1 >> 4) & 3) ^ ((r1s >> 3) << 1)) * 8;
  const unsigned short* aR0 = A  + (rowBase + row0) * LL + col0;
  const unsigned short* aR1 = A  + (rowBase + row1) * LL + col1;
  const unsigned short* bR0 = Bm + (colBase + row0) * LL + col0;
  const unsigned short* bR1 = Bm + (colBase + row1) * LL + col1;
  const int rr = lane & 15, gg = lane >> 4;
  const int rdswz = rr * 64 + ((gg ^ ((rr >> 3) << 1)) << 4);
  f32x4 acc[8][4] = {};
  // ---- prologue: stage halves s0..s6 ----
  STAGE2(aR0 +  0, aR1 +  0, LDS_A + 0);            // t0 A-k0
  STAGE2(bR0 +  0, bR1 +  0, LDS_B + 0);            // t0 B-k0
  STAGE2(aR0 + 32, aR1 + 32, LDS_A + 16384);        // t0 A-k1
  STAGE2(bR0 + 32, bR1 + 32, LDS_B + 16384);        // t0 B-k1
  VM4;
  STAGE2(aR0 + 64, aR1 + 64, LDS_A + 32768);        // t1 A-k0
  STAGE2(bR0 + 64, bR1 + 64, LDS_B + 32768);        // t1 B-k0
  STAGE2(aR0 + 96, aR1 + 96, LDS_A + 32768 + 16384);// t1 A-k1
  VM6;
  BAR;
  #pragma unroll 2
  for (int t = 0; t < 64; ++t) {
    const int d = t & 1;
    const char* pA = lds_raw + LDS_A + d * 32768 + wm * 8192 + rdswz;
    const char* pB = lds_raw + LDS_B + d * 32768 + wn * 4096 + rdswz;
    short8 ar[8], bx, by;
    // ---- phase 0: read B-k0 nj{0,1} + A-k0 (8); stage t+1 B-k1 ----
    bx = *(const short8*)(pB + 0);
    by = *(const short8*)(pB + 1024);
    #pragma unroll
    for (int mi = 0; mi < 8; ++mi) ar[mi] = *(const short8*)(pA + mi * 1024);
    if (t <= 62) { size_t kc = (size_t)(t + 1) * 64 + 32;
      STAGE2(bR0 + kc, bR1 + kc, LDS_B + ((t + 1) & 1) * 32768 + 16384); }
    BAR; PRIO1;
    #pragma unroll
    for (int mi = 0; mi < 8; ++mi) {
      acc[mi][0] = MFMA(ar[mi], bx, acc[mi][0]);
      acc[mi][1] = MFMA(ar[mi], by, acc[mi][1]);
    }
    PRIO0; BAR;
    // ---- phase 1: read B-k0 nj{2,3}; stage t+2 A-k0 ----
    bx = *(const short8*)(pB + 2048);
    by = *(const short8*)(pB + 3072);
    if (t <= 61) { size_t kc = (size_t)(t + 2) * 64;
      STAGE2(aR0 + kc, aR1 + kc, LDS_A + d * 32768); }
    BAR; PRIO1;
    #pragma unroll
    for (int mi = 0; mi < 8; ++mi) {
      acc[mi][2] = MFMA(ar[mi], bx, acc[mi][2]);
      acc[mi][3] = MFMA(ar[mi], by, acc[mi][3]);
    }
    PRIO0; BAR;
    // ---- phase 2: read B-k1 nj{2,3} + A-k1 (8); stage t+2 B-k0 ----
    bx = *(const short8*)(pB + 16384 + 2048);
    by = *(const short8*)(pB + 16384 + 3072);
    #pragma unroll
    for (int mi = 0; mi < 8; ++mi) ar[mi] = *(const short8*)(pA + 16384 + mi * 1024);
    if (t <= 61) { size_t kc = (size_t)(t + 2) * 64;
      STAGE2(bR0 + kc, bR1 + kc, LDS_B + d * 32768); }
    BAR; PRIO1;
    #pragma unroll
    for (int mi = 0; mi < 8; ++mi) {
      acc[mi][2] = MFMA(ar[mi], bx, acc[mi][2]);
      acc[mi][3] = MFMA(ar[mi], by, acc[mi][3]);
    }
    PRIO0; BAR;
    // ---- phase 3: read B-k1 nj{0,1}; stage t+2 A-k1; boundary vmcnt ----
    bx = *(const short8*)(pB + 16384);
    by = *(const short8*)(pB + 16384 + 1024);
    if (t <= 61) { size_t kc = (size_t)(t + 2) * 64 + 32;
      STAGE2(aR0 + kc, aR1 + kc, LDS_A + d * 32768 + 16384); }
    BAR; PRIO1;
    #pragma unroll
    for (int mi = 0; mi < 8; ++mi) {
      acc[mi][0] = MFMA(ar[mi], bx, acc[mi][0]);
      acc[mi][1] = MFMA(ar[mi], by, acc[mi][1]);
    }
    PRIO0;
    if (t < 62) { VM6; } else { VM0; }
    BAR;
  }
  // ---- epilogue: +bm, ReLU, bf16 store ----
  const int co = lane & 15, ro4 = (lane >> 4) * 4;
  #pragma unroll
  for (int mig = 0; mig < 8; ++mig) {
    size_t r0 = rowBase + (size_t)wm * 128 + mig * 16 + ro4;
    #pragma unroll
    for (int nj = 0; nj < 4; ++nj) {
      size_t c = colBase + (size_t)wn * 64 + nj * 16 + co;
      float bc = bm[c];
      #pragma unroll
      for (int j = 0; j < 4; ++j) {
        float v = acc[mig][nj][j] + bc;
        v = fmaxf(v, 0.f);
        C[(r0 + j) * LL + c] = f2bf(v);
      }
    }
  }
}

// ---------------- K6: aggregation ----------------
// rst[d,b,l] = sum_s w_t[b][d][s] * out[s,b,l] + bias[l]. Thread owns 2 l;
// w addresses wave-uniform -> scalar loads.
__global__ __launch_bounds__(256) void k_agg2(const float* __restrict__ w_t,
    const unsigned short* __restrict__ outb, const float* __restrict__ bias,
    float* __restrict__ rst) {
  int b = blockIdx.y;
  int t = threadIdx.x;
  int l0 = blockIdx.x * 512 + t * 2;
  float oA[64], oB[64];
  #pragma unroll
  for (int s = 0; s < 64; ++s) {
    unsigned u = *(const unsigned*)&outb[((size_t)s * BB + b) * LL + l0];
    oA[s] = bf2f((unsigned short)(u & 0xFFFF));
    oB[s] = bf2f((unsigned short)(u >> 16));
  }
  const float* wb = w_t + (size_t)b * 4096;
  float bs0 = bias[l0], bs1 = bias[l0 + 1];
  #pragma unroll 2
  for (int d = 0; d < 64; ++d) {
    const float* wr = wb + d * 64;
    float a0 = 0.f, a1 = 0.f;
    #pragma unroll
    for (int q = 0; q < 16; ++q) {
      f32x4 wq = *(const f32x4*)&wr[q * 4];
      #pragma unroll
      for (int j = 0; j < 4; ++j) {
        float wv = wq[j];
        a0 += wv * oA[q * 4 + j];
        a1 += wv * oB[q * 4 + j];
      }
    }
    f32x2 o; o[0] = a0 + bs0; o[1] = a1 + bs1;
    *(f32x2*)&rst[((size_t)d * BB + b) * LL + l0] = o;
  }
}

extern "C" void kernel_launch(void* const* d_in, const int* in_sizes, int n_in,
                              void* d_out, int out_size, void* d_ws, size_t ws_size,
                              hipStream_t stream) {
  (void)in_sizes; (void)n_in; (void)out_size; (void)ws_size;
  const float* feat  = (const float*)d_in[0];
  const float* Wl    = (const float*)d_in[1];
  const float* bl    = (const float*)d_in[2];
  const float* Wr    = (const float*)d_in[3];
  const float* br    = (const float*)d_in[4];
  const float* Wm    = (const float*)d_in[5];
  const float* bm    = (const float*)d_in[6];
  const float* gamma = (const float*)d_in[7];
  const float* beta  = (const float*)d_in[8];
  const float* bias  = (const float*)d_in[9];
  char* ws = (char*)d_ws;
  unsigned short* feat_bf = (unsigned short*)(ws);                 // 67,108,864
  unsigned short* wm_bf   = (unsigned short*)(ws + 67108864ull);   // 33,554,432
  unsigned short* out_bf  = (unsigned short*)(ws + 100663296ull);  // 67,108,864
  float* attP  = (float*)(ws + 167772160ull);                      //  4,194,304
  float* w_t   = (float*)(ws + 171966464ull);                      //  2,097,152
  unsigned short* wt_bf = (unsigned short*)(ws + 174063616ull);    //    262,144
  float* rst = (float*)d_out;

  k_cvtw<<<dim3(2056), dim3(256), 0, stream>>>(Wm, Wl, Wr, wm_bf, wt_bf);
  k_cvtf<<<dim3(2048), dim3(256), 0, stream>>>(feat, feat_bf);
  k_attm<<<dim3(128, 4), dim3(256), 0, stream>>>(feat_bf, wt_bf, attP);
  k_edge<<<dim3(64), dim3(256), 0, stream>>>(attP, bl, br, gamma, beta, w_t);
  k_gemm8<<<dim3(512), dim3(512), 0, stream>>>(feat_bf, wm_bf, bm, out_bf);
  k_agg2<<<dim3(8, 128), dim3(256), 0, stream>>>(w_t, out_bf, bias, rst);
}

// Round 5
// 442.308 us; speedup vs baseline: 1.0809x; 1.0809x over previous
//
#include <hip/hip_runtime.h>
#include <stdint.h>
#include <stddef.h>

#define NN 64
#define BB 128
#define LL 4096
#define EE 16

typedef __attribute__((ext_vector_type(4))) float f32x4;
typedef __attribute__((ext_vector_type(2))) float f32x2;
typedef __attribute__((ext_vector_type(8))) short short8;
typedef __attribute__((ext_vector_type(4))) unsigned short u16x4;

__device__ __forceinline__ unsigned short f2bf(float f) {
  union { float f; unsigned u; } v; v.f = f;
  unsigned r = v.u + 0x7FFFu + ((v.u >> 16) & 1u);   // RNE
  return (unsigned short)(r >> 16);
}
__device__ __forceinline__ float bf2f(unsigned short h) {
  union { unsigned u; float f; } v; v.u = ((unsigned)h) << 16;
  return v.f;
}
__device__ __forceinline__ void gload16(const void* g, void* l) {
  __builtin_amdgcn_global_load_lds((const __attribute__((address_space(1))) void*)g,
                                   (__attribute__((address_space(3))) void*)l,
                                   16, 0, 0);
}

#define MFMA(a, b, c) __builtin_amdgcn_mfma_f32_16x16x32_bf16((a), (b), (c), 0, 0, 0)

// ---------------- K1: Wm -> bf16 + Wl/Wr -> transposed bf16 ----------------
__global__ __launch_bounds__(256) void k_cvtw(const float* __restrict__ Wm,
    const float* __restrict__ Wl, const float* __restrict__ Wr,
    unsigned short* __restrict__ wm_bf, unsigned short* __restrict__ wt_bf) {
  int bid = blockIdx.x;
  if (bid < 2048) {
    int i = bid * 256 + threadIdx.x;
    for (; i < (LL * LL / 4); i += 2048 * 256) {
      f32x4 v = ((const f32x4*)Wm)[i];
      u16x4 o;
      o[0] = f2bf(v[0]); o[1] = f2bf(v[1]); o[2] = f2bf(v[2]); o[3] = f2bf(v[3]);
      ((u16x4*)wm_bf)[i] = o;
    }
  } else {
    // wt_bf[e][k]: e<16 -> Wl[k][e], e>=16 -> Wr[k][e-16]. 32x4096 bf16.
    int u = (bid - 2048) * 256 + threadIdx.x;   // 0..2047
    int e = u >> 6;
    int kb = (u & 63) * 64;
    const float* src = (e < 16) ? (Wl + e) : (Wr + (e - 16));
    for (int k = kb; k < kb + 64; ++k)
      wt_bf[(size_t)e * LL + k] = f2bf(src[(size_t)k * 16]);
  }
}

// ---------------- K2: fused feat->bf16 convert + MFMA att projections ----------------
// Block = (rowTile, kc): 64 rows x 2048 K. Stages 64x512 bf16 chunks into
// XOR-swizzled LDS (coalesced fp32 reads, feat_bf written on the way),
// A-frags from LDS, B-frags from L2-hot wt_bf. attP[kc] partial sums.
__global__ __launch_bounds__(256) void k_attF(const float* __restrict__ feat,
    const unsigned short* __restrict__ wt_bf,
    unsigned short* __restrict__ feat_bf, float* __restrict__ attP) {
  __shared__ __align__(16) unsigned short alds[64 * 512];
  const int t = threadIdx.x, lane = t & 63, w = t >> 6;
  const int rowBase = blockIdx.x * 64;
  const int kBase = blockIdx.y * 2048;
  const int rr = lane & 15, gg8 = (lane >> 4) * 8;
  f32x4 acc0 = {}, acc1 = {};
  const unsigned short* b0P = wt_bf + (size_t)rr * LL;
  const unsigned short* b1P = wt_bf + (size_t)(16 + rr) * LL;
  for (int c = 0; c < 4; ++c) {
    const int k0 = kBase + c * 512;
    __syncthreads();
    #pragma unroll
    for (int u = 0; u < 32; ++u) {
      int unit = t + u * 256;
      int row = unit >> 7, col4 = unit & 127;
      size_t gi = (size_t)(rowBase + row) * LL + k0 + col4 * 4;
      f32x4 v = *(const f32x4*)&feat[gi];
      u16x4 o; o[0] = f2bf(v[0]); o[1] = f2bf(v[1]); o[2] = f2bf(v[2]); o[3] = f2bf(v[3]);
      *(u16x4*)&feat_bf[gi] = o;
      int byte = (row * 1024 + col4 * 8) ^ ((row & 7) << 4);
      *(u16x4*)((char*)alds + byte) = o;
    }
    __syncthreads();
    const int arow = w * 16 + rr;
    const char* aBase = (const char*)alds + arow * 1024;
    const int axor = (arow & 7) << 4;
    #pragma unroll 4
    for (int ks = 0; ks < 16; ++ks) {
      int abyte = ((ks * 32 + gg8) * 2) ^ axor;
      short8 av = *(const short8*)(aBase + abyte);
      short8 b0 = *(const short8*)(b0P + k0 + ks * 32 + gg8);
      short8 b1 = *(const short8*)(b1P + k0 + ks * 32 + gg8);
      acc0 = MFMA(av, b0, acc0);
      acc1 = MFMA(av, b1, acc1);
    }
  }
  const int orow = rowBase + w * 16 + (lane >> 4) * 4;
  float* P = attP + (size_t)blockIdx.y * (8192 * 32);
  #pragma unroll
  for (int j = 0; j < 4; ++j) {
    P[(size_t)(orow + j) * 32 + rr]      = acc0[j];
    P[(size_t)(orow + j) * 32 + 16 + rr] = acc1[j];
  }
}

// ---------------- K3: edge scores + BN + softmax (sums 2 attP partials) ----------------
__global__ __launch_bounds__(256) void k_edge(const float* __restrict__ attP,
    const float* __restrict__ bl, const float* __restrict__ br,
    const float* __restrict__ gamma, const float* __restrict__ beta,
    float* __restrict__ w_t) {
  __shared__ __align__(16) float attr[BB][20];
  __shared__ float el[NN][BB + 1];
  __shared__ float part[NN][4][2];
  __shared__ float sc[NN], sh[NN];
  int d = blockIdx.x, t = threadIdx.x;
  for (int i = t; i < 2048; i += 256) {
    int b = i >> 4, e = i & 15;
    float v2 = br[e];
    #pragma unroll
    for (int c = 0; c < 2; ++c)
      v2 += attP[(size_t)c * (8192 * 32) + ((size_t)d * 128 + b) * 32 + 16 + e];
    attr[b][e] = v2;
  }
  float blv[16];
  #pragma unroll
  for (int e = 0; e < 16; ++e) blv[e] = bl[e];
  __syncthreads();
  for (int v = t; v < NN * BB; v += 256) {
    int s = v >> 7, b = v & 127;
    float al[16];
    #pragma unroll
    for (int e = 0; e < 16; ++e) al[e] = blv[e];
    #pragma unroll
    for (int c = 0; c < 2; ++c) {
      const f32x4* p = (const f32x4*)&attP[(size_t)c * (8192 * 32) + ((size_t)s * 128 + b) * 32];
      #pragma unroll
      for (int q = 0; q < 4; ++q) {
        f32x4 x = p[q];
        al[q * 4 + 0] += x[0]; al[q * 4 + 1] += x[1];
        al[q * 4 + 2] += x[2]; al[q * 4 + 3] += x[3];
      }
    }
    float acc = 0.f;
    #pragma unroll
    for (int e = 0; e < 16; ++e) acc += al[e] * attr[b][e];
    el[s][b] = acc;
  }
  __syncthreads();
  {
    int s = t >> 2, q = t & 3;
    float sum = 0.f, ss = 0.f;
    for (int b = q * 32; b < q * 32 + 32; ++b) { float x = el[s][b]; sum += x; ss += x * x; }
    part[s][q][0] = sum; part[s][q][1] = ss;
  }
  __syncthreads();
  if (t < 64) {
    float sum = 0.f, ss = 0.f;
    #pragma unroll
    for (int q = 0; q < 4; ++q) { sum += part[t][q][0]; ss += part[t][q][1]; }
    float mu = sum * (1.f / 128.f);
    float var = ss * (1.f / 128.f) - mu * mu;
    int c = d * 64 + t;
    float a = gamma[c] * rsqrtf(fmaxf(var, 0.f) + 1e-5f);
    sc[t] = a; sh[t] = beta[c] - mu * a;
  }
  __syncthreads();
  if (t < 128) {
    int b = t;
    float y[64];
    float m = -1e30f;
    #pragma unroll
    for (int s = 0; s < 64; ++s) { y[s] = sc[s] * el[s][b] + sh[s]; m = fmaxf(m, y[s]); }
    float sum = 0.f;
    #pragma unroll
    for (int s = 0; s < 64; ++s) { y[s] = __expf(y[s] - m); sum += y[s]; }
    float inv = 1.f / sum;
    float* wp = &w_t[((size_t)b * 64 + d) * 64];
    #pragma unroll
    for (int s4 = 0; s4 < 16; ++s4) {
      f32x4 o;
      o[0] = y[s4 * 4 + 0] * inv; o[1] = y[s4 * 4 + 1] * inv;
      o[2] = y[s4 * 4 + 2] * inv; o[3] = y[s4 * 4 + 3] * inv;
      *(f32x4*)&wp[s4 * 4] = o;
    }
  }
}

// ---------------- K4: 256x256 8-phase bf16 MFMA GEMM, balanced reads ----------------
// R4->R5: phase reads rebalanced 10/2/10/2 -> 8/4/8/4 (A-rows split across
// phases, B read whole per k-half). Staging ring re-derived: each slot staged
// exactly one phase after its last read; VM4 mid-tile + VM8 boundary
// (tail: VM2/VM0), ring depth 8 gloads.
#define LDS_A 0
#define LDS_B 65536
#define BAR   __builtin_amdgcn_s_barrier()
#define VM8   asm volatile("s_waitcnt vmcnt(8)" ::: "memory")
#define VM4   asm volatile("s_waitcnt vmcnt(4)" ::: "memory")
#define VM2   asm volatile("s_waitcnt vmcnt(2)" ::: "memory")
#define VM0   asm volatile("s_waitcnt vmcnt(0)" ::: "memory")
#define PRIO1 __builtin_amdgcn_s_setprio(1)
#define PRIO0 __builtin_amdgcn_s_setprio(0)
#define STAGE2(g0, g1, ldsoff) do { \
    gload16((g0), lds_raw + (ldsoff) + tid16); \
    gload16((g1), lds_raw + (ldsoff) + 8192 + tid16); } while (0)

__global__ __launch_bounds__(512, 2) void k_gemm8(const unsigned short* __restrict__ A,
    const unsigned short* __restrict__ Bm, const float* __restrict__ bm,
    unsigned short* __restrict__ C) {
  __shared__ __align__(16) char lds_raw[131072];
  const int tid = threadIdx.x;
  const int lane = tid & 63, wave = tid >> 6;
  const int wm = wave >> 2, wn = wave & 3;
  int bid = blockIdx.x;
  int swz = (bid & 7) * 64 + (bid >> 3);
  int tM = swz >> 4, tN = swz & 15;
  const size_t rowBase = (size_t)tM * 256, colBase = (size_t)tN * 256;
  const int tid16 = tid * 16;
  const int o0 = tid16, o1 = tid16 + 8192;
  const int r0s = (o0 & 1023) >> 6, r1s = (o1 & 1023) >> 6;
  const int row0 = (o0 >> 10) * 16 + r0s, row1 = (o1 >> 10) * 16 + r1s;
  const int col0 = (((o0 >> 4) & 3) ^ ((r0s >> 3) << 1)) * 8;
  const int col1 = (((o1 >> 4) & 3) ^ ((r1s >> 3) << 1)) * 8;
  const unsigned short* aR0 = A  + (rowBase + row0) * LL + col0;
  const unsigned short* aR1 = A  + (rowBase + row1) * LL + col1;
  const unsigned short* bR0 = Bm + (colBase + row0) * LL + col0;
  const unsigned short* bR1 = Bm + (colBase + row1) * LL + col1;
  const int rr = lane & 15, gg = lane >> 4;
  const int rdswz = rr * 64 + ((gg ^ ((rr >> 3) << 1)) << 4);
  f32x4 acc[8][4] = {};
  // ---- prologue: A-k0[0],B-k0[0],A-k1[0],B-k1[0],B-k0[1],A-k0[1] ----
  STAGE2(aR0 +  0, aR1 +  0, LDS_A + 0);
  STAGE2(bR0 +  0, bR1 +  0, LDS_B + 0);
  STAGE2(aR0 + 32, aR1 + 32, LDS_A + 16384);
  STAGE2(bR0 + 32, bR1 + 32, LDS_B + 16384);
  STAGE2(bR0 + 64, bR1 + 64, LDS_B + 32768);
  STAGE2(aR0 + 64, aR1 + 64, LDS_A + 32768);
  VM8;
  BAR;
  #pragma unroll 2
  for (int t = 0; t < 64; ++t) {
    const int d = t & 1;
    const char* pA = lds_raw + LDS_A + d * 32768 + wm * 8192 + rdswz;
    const char* pB = lds_raw + LDS_B + d * 32768 + wn * 4096 + rdswz;
    short8 ar[4], bf4[4];
    // ---- P0: read A-k0 mi0-3 + B-k0 nj0-3; stage (t+1) A-k1 ----
    #pragma unroll
    for (int i = 0; i < 4; ++i) bf4[i] = *(const short8*)(pB + i * 1024);
    #pragma unroll
    for (int i = 0; i < 4; ++i) ar[i] = *(const short8*)(pA + i * 1024);
    if (t <= 62) { size_t kk = (size_t)(t + 1) * 64 + 32;
      STAGE2(aR0 + kk, aR1 + kk, LDS_A + ((t + 1) & 1) * 32768 + 16384); }
    BAR; PRIO1;
    #pragma unroll
    for (int i = 0; i < 4; ++i) {
      acc[i][0] = MFMA(ar[i], bf4[0], acc[i][0]);
      acc[i][1] = MFMA(ar[i], bf4[1], acc[i][1]);
      acc[i][2] = MFMA(ar[i], bf4[2], acc[i][2]);
      acc[i][3] = MFMA(ar[i], bf4[3], acc[i][3]);
    }
    PRIO0; BAR;
    // ---- P1: read A-k0 mi4-7; stage (t+2) B-k0; mid vmcnt ----
    #pragma unroll
    for (int i = 0; i < 4; ++i) ar[i] = *(const short8*)(pA + 4096 + i * 1024);
    if (t <= 61) { size_t kk = (size_t)(t + 2) * 64;
      STAGE2(bR0 + kk, bR1 + kk, LDS_B + d * 32768); }
    BAR; PRIO1;
    #pragma unroll
    for (int i = 0; i < 4; ++i) {
      acc[4 + i][0] = MFMA(ar[i], bf4[0], acc[4 + i][0]);
      acc[4 + i][1] = MFMA(ar[i], bf4[1], acc[4 + i][1]);
      acc[4 + i][2] = MFMA(ar[i], bf4[2], acc[4 + i][2]);
      acc[4 + i][3] = MFMA(ar[i], bf4[3], acc[4 + i][3]);
    }
    PRIO0;
    if (t <= 61) { VM4; } else if (t == 62) { VM2; } else { VM0; }
    BAR;
    // ---- P2: read A-k1 mi0-3 + B-k1 nj0-3; stage (t+2) A-k0 ----
    #pragma unroll
    for (int i = 0; i < 4; ++i) bf4[i] = *(const short8*)(pB + 16384 + i * 1024);
    #pragma unroll
    for (int i = 0; i < 4; ++i) ar[i] = *(const short8*)(pA + 16384 + i * 1024);
    if (t <= 61) { size_t kk = (size_t)(t + 2) * 64;
      STAGE2(aR0 + kk, aR1 + kk, LDS_A + d * 32768); }
    BAR; PRIO1;
    #pragma unroll
    for (int i = 0; i < 4; ++i) {
      acc[i][0] = MFMA(ar[i], bf4[0], acc[i][0]);
      acc[i][1] = MFMA(ar[i], bf4[1], acc[i][1]);
      acc[i][2] = MFMA(ar[i], bf4[2], acc[i][2]);
      acc[i][3] = MFMA(ar[i], bf4[3], acc[i][3]);
    }
    PRIO0; BAR;
    // ---- P3: read A-k1 mi4-7; stage (t+1) B-k1; boundary vmcnt ----
    #pragma unroll
    for (int i = 0; i < 4; ++i) ar[i] = *(const short8*)(pA + 16384 + 4096 + i * 1024);
    if (t <= 62) { size_t kk = (size_t)(t + 1) * 64 + 32;
      STAGE2(bR0 + kk, bR1 + kk, LDS_B + ((t + 1) & 1) * 32768 + 16384); }
    BAR; PRIO1;
    #pragma unroll
    for (int i = 0; i < 4; ++i) {
      acc[4 + i][0] = MFMA(ar[i], bf4[0], acc[4 + i][0]);
      acc[4 + i][1] = MFMA(ar[i], bf4[1], acc[4 + i][1]);
      acc[4 + i][2] = MFMA(ar[i], bf4[2], acc[4 + i][2]);
      acc[4 + i][3] = MFMA(ar[i], bf4[3], acc[4 + i][3]);
    }
    PRIO0;
    if (t <= 61) { VM8; } else { VM4; }
    BAR;
  }
  VM0;
  // ---- epilogue: +bm, ReLU, bf16 store ----
  const int co = lane & 15, ro4 = (lane >> 4) * 4;
  #pragma unroll
  for (int mig = 0; mig < 8; ++mig) {
    size_t r0 = rowBase + (size_t)wm * 128 + mig * 16 + ro4;
    #pragma unroll
    for (int nj = 0; nj < 4; ++nj) {
      size_t c = colBase + (size_t)wn * 64 + nj * 16 + co;
      float bc = bm[c];
      #pragma unroll
      for (int j = 0; j < 4; ++j) {
        float v = acc[mig][nj][j] + bc;
        v = fmaxf(v, 0.f);
        C[(r0 + j) * LL + c] = f2bf(v);
      }
    }
  }
}

// ---------------- K5: aggregation ----------------
__global__ __launch_bounds__(256) void k_agg2(const float* __restrict__ w_t,
    const unsigned short* __restrict__ outb, const float* __restrict__ bias,
    float* __restrict__ rst) {
  int b = blockIdx.y;
  int t = threadIdx.x;
  int l0 = blockIdx.x * 512 + t * 2;
  float oA[64], oB[64];
  #pragma unroll
  for (int s = 0; s < 64; ++s) {
    unsigned u = *(const unsigned*)&outb[((size_t)s * BB + b) * LL + l0];
    oA[s] = bf2f((unsigned short)(u & 0xFFFF));
    oB[s] = bf2f((unsigned short)(u >> 16));
  }
  const float* wb = w_t + (size_t)b * 4096;
  float bs0 = bias[l0], bs1 = bias[l0 + 1];
  #pragma unroll 2
  for (int d = 0; d < 64; ++d) {
    const float* wr = wb + d * 64;
    float a0 = 0.f, a1 = 0.f;
    #pragma unroll
    for (int q = 0; q < 16; ++q) {
      f32x4 wq = *(const f32x4*)&wr[q * 4];
      #pragma unroll
      for (int j = 0; j < 4; ++j) {
        float wv = wq[j];
        a0 += wv * oA[q * 4 + j];
        a1 += wv * oB[q * 4 + j];
      }
    }
    f32x2 o; o[0] = a0 + bs0; o[1] = a1 + bs1;
    *(f32x2*)&rst[((size_t)d * BB + b) * LL + l0] = o;
  }
}

extern "C" void kernel_launch(void* const* d_in, const int* in_sizes, int n_in,
                              void* d_out, int out_size, void* d_ws, size_t ws_size,
                              hipStream_t stream) {
  (void)in_sizes; (void)n_in; (void)out_size; (void)ws_size;
  const float* feat  = (const float*)d_in[0];
  const float* Wl    = (const float*)d_in[1];
  const float* bl    = (const float*)d_in[2];
  const float* Wr    = (const float*)d_in[3];
  const float* br    = (const float*)d_in[4];
  const float* Wm    = (const float*)d_in[5];
  const float* bm    = (const float*)d_in[6];
  const float* gamma = (const float*)d_in[7];
  const float* beta  = (const float*)d_in[8];
  const float* bias  = (const float*)d_in[9];
  char* ws = (char*)d_ws;
  unsigned short* feat_bf = (unsigned short*)(ws);                 // 67,108,864
  unsigned short* wm_bf   = (unsigned short*)(ws + 67108864ull);   // 33,554,432
  unsigned short* out_bf  = (unsigned short*)(ws + 100663296ull);  // 67,108,864
  float* attP  = (float*)(ws + 167772160ull);                      //  2,097,152
  float* w_t   = (float*)(ws + 169869312ull);                      //  2,097,152
  unsigned short* wt_bf = (unsigned short*)(ws + 171966464ull);    //    262,144
  float* rst = (float*)d_out;

  k_cvtw<<<dim3(2056), dim3(256), 0, stream>>>(Wm, Wl, Wr, wm_bf, wt_bf);
  k_attF<<<dim3(128, 2), dim3(256), 0, stream>>>(feat, wt_bf, feat_bf, attP);
  k_edge<<<dim3(64), dim3(256), 0, stream>>>(attP, bl, br, gamma, beta, w_t);
  k_gemm8<<<dim3(512), dim3(512), 0, stream>>>(feat_bf, wm_bf, bm, out_bf);
  k_agg2<<<dim3(8, 128), dim3(256), 0, stream>>>(w_t, out_bf, bias, rst);
}